// Round 5
// baseline (237.643 us; speedup 1.0000x reference)
//
#include <hip/hip_runtime.h>
#include <hip/hip_cooperative_groups.h>

namespace cg = cooperative_groups;

typedef unsigned short u16;
typedef unsigned int   u32;
typedef unsigned long long u64;

typedef __bf16 bf16x8 __attribute__((ext_vector_type(8)));
typedef float  f32x4  __attribute__((ext_vector_type(4)));

#define MFMA_BF16(a,b,c) __builtin_amdgcn_mfma_f32_16x16x32_bf16((a),(b),(c),0,0,0)

__device__ __forceinline__ float bf2f(u16 u) {
    return __uint_as_float(((u32)u) << 16);
}
__device__ __forceinline__ u16 f2bf(float x) {
    u32 u = __float_as_uint(x);
    u += 0x7fffu + ((u >> 16) & 1u);   // RNE
    return (u16)(u >> 16);
}
__device__ __forceinline__ float ldany(const void* p, size_t i, int f32) {
    return f32 ? ((const float*)p)[i] : bf2f(((const u16*)p)[i]);
}
// fp32-vs-bf16 detect from first 64 words of h; identical in every wave.
__device__ __forceinline__ int detect_f32(const u32* hw) {
    u32 w = hw[threadIdx.x & 63];
    int e = (w >> 23) & 0xFF;
    u64 m = __ballot(e >= 64 && e <= 190);
    return __popcll(m) >= 32 ? 1 : 0;
}

// ---------------- LDS layouts (union across phases) ----------------------
struct __align__(16) K2LDS {
    u16 At[64 * 68];
    union { u16 Bt[256 * 68]; u16 Ct[256 * 68]; };
    float wa1s[256], wa2s[256];
    float s1[64], s2[64];
};
struct __align__(16) K4LDS {
    u32   vpack[2048];                 // 8192 B
    u16   sjb[2048];                   // 4096 B
    u64   mw[64 * 33];                 // 16896 B
    float u1[64], u2[64], nsi[64], inv[64];
    float lred[1024];                  // 4096 B
    u16   Pt[2][8192];                 // 2 x 16384 B, [octet][row][8]
    int   claim[2];
};
struct __align__(16) FusedLDS {
    union {
        struct { float s1[16], s2[16]; } p0;
        struct { float wmax[16]; } p3;
        K2LDS p2;
        K4LDS p4;
    };
};

// ---------------- single cooperative kernel: 256 blocks x 1024 thr -------
// P0: W^T + Wa1/Wa2 (blocks<64) + cnt zero   } before sync1 (independent)
// P1: adj -> mask bitset (all blocks)        }
// P2: Whb_t = bf16((h@W)^T) + exact fp32 s_i/s_j   (k2 math verbatim)
// P3: per-batch shift + factored-exp tables        (k3n verbatim, blocks<8)
// P4: attention MFMA + ELU                         (k4 verbatim, 47us form)
__global__ __launch_bounds__(1024, 4) void fused(
        const void* __restrict__ h, const int* __restrict__ adj,
        const void* __restrict__ w, const void* __restrict__ a,
        u16* __restrict__ wt, float* __restrict__ wa1, float* __restrict__ wa2,
        float* __restrict__ sig, float* __restrict__ sjg,
        float* __restrict__ u1g, float* __restrict__ u2g,
        u32* __restrict__ vpackg, u16* __restrict__ sjbfg,
        u64* __restrict__ mb64, u16* __restrict__ whbt,
        void* __restrict__ out, int* __restrict__ cnt) {
    __shared__ FusedLDS U;
    cg::grid_group gg = cg::this_grid();
    int f32 = detect_f32((const u32*)h);
    int t = threadIdx.x, bid = blockIdx.x;
    int wid = t >> 6, lane = t & 63, ln = lane & 15, qd = lane >> 4;

    // ---- P0: WT + Wa1/Wa2 (4 k-rows per block, blocks 0..63) ----
    if (bid < 64) {
        int g = t >> 8, o = t & 255;
        int k = bid * 4 + g;
        float wv = ldany(w, (size_t)k * 256 + o, f32);
        wt[o * 256 + k] = f2bf(wv);
        float p1 = wv * ldany(a, o, f32);
        float p2 = wv * ldany(a, 256 + o, f32);
        for (int d = 32; d; d >>= 1) { p1 += __shfl_down(p1, d); p2 += __shfl_down(p2, d); }
        if (lane == 0) { U.p0.s1[wid] = p1; U.p0.s2[wid] = p2; }
        __syncthreads();
        if (o == 0) {
            wa1[k] = U.p0.s1[g * 4] + U.p0.s1[g * 4 + 1] + U.p0.s1[g * 4 + 2] + U.p0.s1[g * 4 + 3];
            wa2[k] = U.p0.s2[g * 4] + U.p0.s2[g * 4 + 1] + U.p0.s2[g * 4 + 2] + U.p0.s2[g * 4 + 3];
        }
    }
    if (bid == 0 && t < 8) cnt[t] = 0;

    // ---- P1: mask bitset (16 u64 words per wave; loads batched) ----
    {
        int base = bid * 256 + wid * 16;               // 65536 words total
        u32 va[16];
        #pragma unroll
        for (int q = 0; q < 16; q++) {
            int idx = base + q;
            int mrow = idx >> 5, c = idx & 31;
            int j = c * 64 + lane;
            va[q] = (u32)(adj[(size_t)mrow * 2048 + j] > 0) | (u32)(j == mrow);
        }
        #pragma unroll
        for (int q = 0; q < 16; q++) {
            u64 m = __ballot(va[q] != 0);
            if (lane == 0) mb64[base + q] = m;
        }
    }

    gg.sync();

    // ---- P2: Whb_t + exact fp32 s_i/s_j (k2 math; A on t<512, B on t>=512) ----
    {
        K2LDS& L = U.p2;
        int m0 = bid * 64;
        int b  = m0 >> 11;
        int n0 = m0 & 2047;
        if (t < 256) { L.wa1s[t] = wa1[t]; L.wa2s[t] = wa2[t]; }
        if (t < 64) { L.s1[t] = 0.f; L.s2[t] = 0.f; }
        __syncthreads();

        float a1 = 0.f, a2 = 0.f;
        f32x4 acc[4];
        for (int mi = 0; mi < 4; mi++) acc[mi] = (f32x4){0.f, 0.f, 0.f, 0.f};

        for (int c = 0; c < 4; c++) {
            int k0c = c * 64;
            if (t < 512) {
                int r = t >> 3, s = t & 7;              // 64 rows x 8 octets
                float xv[8]; u16 uv[8];
                if (f32) {
                    const float* src = (const float*)h + (size_t)(m0 + r) * 256 + k0c + s * 8;
                    f32x4 x0 = *(const f32x4*)src;
                    f32x4 x1 = *(const f32x4*)(src + 4);
                    #pragma unroll
                    for (int q = 0; q < 4; q++) { xv[q] = x0[q]; xv[4 + q] = x1[q]; }
                    #pragma unroll
                    for (int q = 0; q < 8; q++) uv[q] = f2bf(xv[q]);
                } else {
                    const u16* src = (const u16*)h + (size_t)(m0 + r) * 256 + k0c + s * 8;
                    *(uint4*)uv = *(const uint4*)src;
                    #pragma unroll
                    for (int q = 0; q < 8; q++) xv[q] = bf2f(uv[q]);
                }
                *(uint4*)&L.At[r * 68 + s * 8] = *(uint4*)uv;
                float pa = 0.f, pb = 0.f;
                #pragma unroll
                for (int q = 0; q < 8; q++) {
                    pa += xv[q] * L.wa1s[k0c + s * 8 + q];
                    pb += xv[q] * L.wa2s[k0c + s * 8 + q];
                }
                a1 += pa; a2 += pb;
            } else {
                int tt = t - 512;
                #pragma unroll
                for (int p = 0; p < 4; p++) {
                    int f = (tt >> 3) + p * 64, s = tt & 7;   // 256 f rows
                    *(uint4*)&L.Bt[f * 68 + s * 8] =
                        *(const uint4*)(wt + (size_t)f * 256 + k0c + s * 8);
                }
            }
            __syncthreads();
            for (int ks = 0; ks < 2; ks++) {
                bf16x8 af[4], bfr;
                for (int mi = 0; mi < 4; mi++)
                    af[mi] = *(const bf16x8*)&L.At[(mi * 16 + ln) * 68 + ks * 32 + qd * 8];
                bfr = *(const bf16x8*)&L.Bt[(wid * 16 + ln) * 68 + ks * 32 + qd * 8];
                for (int mi = 0; mi < 4; mi++)
                    acc[mi] = MFMA_BF16(af[mi], bfr, acc[mi]);
            }
            __syncthreads();
        }

        if (t < 512) {
            atomicAdd(&L.s1[t >> 3], a1);
            atomicAdd(&L.s2[t >> 3], a2);
        }
        // transpose via LDS: Ct[f][n-local], then contiguous linear stores
        for (int mi = 0; mi < 4; mi++) {
            int f = wid * 16 + ln;
            int n = mi * 16 + qd * 4;
            u16 v[4];
            for (int r = 0; r < 4; r++) v[r] = f2bf(acc[mi][r]);
            *(uint2*)&L.Ct[f * 68 + n] = *(uint2*)v;
        }
        __syncthreads();
        if (t < 64) { sig[m0 + t] = L.s1[t]; sjg[m0 + t] = L.s2[t]; }
        {
            int fr = t >> 2, q0 = (t & 3) * 2;          // 256 rows x 4 quarter-pairs
            size_t base = (size_t)b * 524288 + (size_t)fr * 2048 + n0;
            #pragma unroll
            for (int k = 0; k < 2; k++) {
                int s = q0 + k;
                uint4 v = *(uint4*)&L.Ct[fr * 68 + s * 8];
                *(uint4*)(whbt + base + s * 8) = v;
            }
        }
    }

    gg.sync();

    // ---- P3: per-batch shift + factored-exp tables (blocks 0..7) ----
    if (bid < 8) {
        const float* sjb = sjg + (size_t)bid * 2048;
        float mx = -3.4e38f;
        if (t < 512) {
            #pragma unroll
            for (int p = 0; p < 4; p++) mx = fmaxf(mx, sjb[t + p * 512]);
        }
        for (int d = 32; d; d >>= 1) mx = fmaxf(mx, __shfl_xor(mx, d));
        if (lane == 0) U.p3.wmax[wid] = mx;
        __syncthreads();
        float Mb = -3.4e38f;
        #pragma unroll
        for (int q = 0; q < 16; q++) Mb = fmaxf(Mb, U.p3.wmax[q]);
        if (t < 512) {
            #pragma unroll
            for (int p = 0; p < 4; p++) {
                int j = t + p * 512;
                float sjv = sjb[j];
                float vj  = __expf(sjv - Mb);
                float v2j = __expf(0.2f * (sjv - Mb));
                vpackg[bid * 2048 + j] = (u32)f2bf(vj) | ((u32)f2bf(v2j) << 16);
                sjbfg[bid * 2048 + j]  = f2bf(sjv);
                float siv = sig[bid * 2048 + j];
                float x = siv + Mb;
                float K = fmaxf(x, 0.2f * x);
                u1g[bid * 2048 + j] = __expf(x - K);
                u2g[bid * 2048 + j] = __expf(0.2f * x - K);
            }
        }
    }

    gg.sync();

    // ---- P4: attention MFMA + ELU (k4 verbatim: 16 waves, 128-j chunks) ----
    {
        K4LDS& L = U.p4;
        if (t == 0) {
            // HW_REG_XCC_ID = id 20, offset 0, size 32 -> imm = 20 | (31<<11)
            int xcd = __builtin_amdgcn_s_getreg(63508) & 7;
            int bsel = 0, tile = 0;
            #pragma unroll
            for (int k = 0; k < 8; k++) {
                int bb = (xcd + k) & 7;
                int tt = atomicAdd(&cnt[bb], 1);
                if (tt < 32) { bsel = bb; tile = tt; break; }
            }
            L.claim[0] = bsel; L.claim[1] = tile;
        }
        __syncthreads();
        int b  = L.claim[0];
        int i0 = L.claim[1] * 64;
        const u16* wb = whbt + (size_t)b * 524288 + (size_t)wid * 16 * 2048;
        float lacc = 0.f;

        bf16x8 br[2][4];
        #define LOAD_B(cc, bb) do {                                             \
            int j0_ = (cc) * 128;                                               \
            _Pragma("unroll")                                                   \
            for (int ks = 0; ks < 4; ks++)                                      \
                br[bb][ks] = *(const bf16x8*)(wb +                              \
                    (size_t)ln * 2048 + j0_ + ks * 32 + qd * 8);                \
        } while (0)

        #define PGEN(cc, bb) do {                                               \
            int r_ = t & 63, o_ = t >> 6;                                       \
            int jb_ = (cc) * 128 + o_ * 8;                                      \
            uint4 pkA_ = *(const uint4*)&L.vpack[jb_];                          \
            uint4 pkB_ = *(const uint4*)&L.vpack[jb_ + 4];                      \
            uint4 sj4_ = *(const uint4*)&L.sjb[jb_];                            \
            u32 mb_ = (u32)(L.mw[r_ * 33 + 2 * (cc) + (o_ >> 3)]                \
                            >> ((o_ & 7) * 8)) & 0xffu;                         \
            float u1_ = L.u1[r_], u2_ = L.u2[r_], nsi_ = L.nsi[r_];             \
            u32 pr_[4];                                                         \
            _Pragma("unroll")                                                   \
            for (int pk = 0; pk < 4; pk++) {                                    \
                u32 vw0_ = (pk == 0) ? pkA_.x : (pk == 1) ? pkA_.z              \
                         : (pk == 2) ? pkB_.x : pkB_.z;                         \
                u32 vw1_ = (pk == 0) ? pkA_.y : (pk == 1) ? pkA_.w              \
                         : (pk == 2) ? pkB_.y : pkB_.w;                         \
                u32 sw_ = (pk == 0) ? sj4_.x : (pk == 1) ? sj4_.y               \
                         : (pk == 2) ? sj4_.z : sj4_.w;                         \
                float sj0_ = __uint_as_float(sw_ << 16);                        \
                float sj1_ = __uint_as_float(sw_ & 0xffff0000u);                \
                float p0_, p1_;                                                 \
                {                                                               \
                    bool pos = sj0_ > nsi_;                                     \
                    float vv = __uint_as_float(pos ? (vw0_ << 16)               \
                                                   : ((vw0_ >> 16) << 16));     \
                    p0_ = (pos ? u1_ : u2_) * vv;                               \
                    p0_ = ((mb_ >> (2 * pk)) & 1u) ? p0_ : 0.f;                 \
                }                                                               \
                {                                                               \
                    bool pos = sj1_ > nsi_;                                     \
                    float vv = __uint_as_float(pos ? (vw1_ << 16)               \
                                                   : ((vw1_ >> 16) << 16));     \
                    p1_ = (pos ? u1_ : u2_) * vv;                               \
                    p1_ = ((mb_ >> (2 * pk + 1)) & 1u) ? p1_ : 0.f;             \
                }                                                               \
                lacc += p0_ + p1_;                                              \
                pr_[pk] = __builtin_amdgcn_perm(__float_as_uint(p1_),           \
                                                __float_as_uint(p0_),           \
                                                0x07060302u);                   \
            }                                                                   \
            *(uint4*)&L.Pt[bb][t * 8] = *(uint4*)pr_;                           \
        } while (0)

        LOAD_B(0, 0);
        for (int p = 0; p < 2; p++) { int idx = t + p * 1024; L.vpack[idx] = vpackg[b * 2048 + idx]; }
        ((u32*)L.sjb)[t] = ((const u32*)(sjbfg + (size_t)b * 2048))[t];
        for (int p = 0; p < 2; p++) {
            int idx = t + p * 1024;                         // 2048 u64 words
            int r = idx >> 5, c = idx & 31;
            L.mw[r * 33 + c] = mb64[(size_t)(i0 + r) * 32 + c];
        }
        if (t < 64) {
            int row = b * 2048 + i0 + t;
            L.u1[t] = u1g[row]; L.u2[t] = u2g[row]; L.nsi[t] = -sig[row];
        }
        __syncthreads();
        PGEN(0, 0);

        f32x4 acc[4];
        for (int mi = 0; mi < 4; mi++)
            acc[mi] = (f32x4){0.f, 0.f, 0.f, 0.f};

        #define STEP(c, cur, nxt) do {                                          \
            __syncthreads();                                                    \
            if ((c) < 15) { LOAD_B((c) + 1, nxt); PGEN((c) + 1, nxt); }         \
            __builtin_amdgcn_s_setprio(1);                                      \
            _Pragma("unroll")                                                   \
            for (int ks = 0; ks < 4; ks++) {                                    \
                bf16x8 af[4];                                                   \
                _Pragma("unroll")                                               \
                for (int mi = 0; mi < 4; mi++)                                  \
                    af[mi] = *(const bf16x8*)&L.Pt[cur][((ks * 4 + qd) * 64 +   \
                                                         mi * 16 + ln) * 8];    \
                _Pragma("unroll")                                               \
                for (int mi = 0; mi < 4; mi++)                                  \
                    acc[mi] = MFMA_BF16(af[mi], br[cur][ks], acc[mi]);          \
            }                                                                   \
            __builtin_amdgcn_s_setprio(0);                                      \
        } while (0)

        for (int cc = 0; cc < 8; cc++) {
            STEP(2 * cc,     0, 1);
            STEP(2 * cc + 1, 1, 0);
        }

        __syncthreads();
        L.lred[t] = lacc;
        __syncthreads();
        if (t < 64) {
            float s = 0.f;
            #pragma unroll
            for (int q = 0; q < 16; q++) s += L.lred[q * 64 + t];
            L.inv[t] = 1.0f / s;
        }
        __syncthreads();

        {
            int fg = wid * 16 + ln;
            for (int mi = 0; mi < 4; mi++) {
                for (int reg = 0; reg < 4; reg++) {
                    int rl = mi * 16 + qd * 4 + reg;
                    float hp = acc[mi][reg] * L.inv[rl];
                    float y = hp > 0.f ? hp : (__expf(hp) - 1.f);
                    size_t idx = (size_t)(b * 2048 + i0 + rl) * 256 + fg;
                    if (f32) ((float*)out)[idx] = y;
                    else     ((u16*)out)[idx]   = f2bf(y);
                }
            }
        }
        #undef LOAD_B
        #undef PGEN
        #undef STEP
    }
}

// ---------------- launch --------------------------------------------------
extern "C" void kernel_launch(void* const* d_in, const int* in_sizes, int n_in,
                              void* d_out, int out_size, void* d_ws, size_t ws_size,
                              hipStream_t stream) {
    const void* h   = d_in[0];              // (8,2048,256) fp32 (detected) or bf16
    const int*  adj = (const int*)d_in[1];  // int32 (2048,2048)
    const void* W   = d_in[2];              // (256,256)
    const void* a   = d_in[3];              // (512,1)

    char* ws = (char*)d_ws;
    u16*   WT    = (u16*)  (ws + 0);        // 131072
    float* si    = (float*)(ws + 131072);   // 65536
    float* sj    = (float*)(ws + 196608);   // 65536
    float* u1    = (float*)(ws + 262144);   // 65536
    float* u2    = (float*)(ws + 327680);   // 65536
    u32*   vpack = (u32*)  (ws + 458752);   // 65536
    u16*   sjbf  = (u16*)  (ws + 524288);   // 32768
    u64*   mb64  = (u64*)  (ws + 557056);   // 524288
    u16*   whbt  = (u16*)  (ws + 1081344);  // 8388608 (end 9469952)
    float* Wa1   = (float*)(ws + 9469952);  // 1024
    float* Wa2   = (float*)(ws + 9470976);  // 1024
    int*   cnt   = (int*)  (ws + 9472000);  // 32

    void* outp = d_out;
    void* kargs[] = {
        (void*)&h, (void*)&adj, (void*)&W, (void*)&a,
        (void*)&WT, (void*)&Wa1, (void*)&Wa2, (void*)&si, (void*)&sj,
        (void*)&u1, (void*)&u2, (void*)&vpack, (void*)&sjbf,
        (void*)&mb64, (void*)&whbt, (void*)&outp, (void*)&cnt
    };
    hipLaunchCooperativeKernel((const void*)fused, dim3(256), dim3(1024),
                               kargs, 0, stream);
}

// Round 6
// 132.811 us; speedup vs baseline: 1.7893x; 1.7893x over previous
//
#include <hip/hip_runtime.h>

typedef unsigned short u16;
typedef unsigned int   u32;
typedef unsigned long long u64;

typedef __bf16 bf16x8 __attribute__((ext_vector_type(8)));
typedef float  f32x4  __attribute__((ext_vector_type(4)));

#define MFMA_BF16(a,b,c) __builtin_amdgcn_mfma_f32_16x16x32_bf16((a),(b),(c),0,0,0)

__device__ __forceinline__ float bf2f(u16 u) {
    return __uint_as_float(((u32)u) << 16);
}
__device__ __forceinline__ u16 f2bf(float x) {
    u32 u = __float_as_uint(x);
    u += 0x7fffu + ((u >> 16) & 1u);   // RNE
    return (u16)(u >> 16);
}
__device__ __forceinline__ float ldany(const void* p, size_t i, int f32) {
    return f32 ? ((const float*)p)[i] : bf2f(((const u16*)p)[i]);
}
// fp32-vs-bf16 detect from first 64 words of h; identical in every wave.
__device__ __forceinline__ int detect_f32(const u32* hw) {
    u32 w = hw[threadIdx.x & 63];
    int e = (w >> 23) & 0xFF;
    u64 m = __ballot(e >= 64 && e <= 190);
    return __popcll(m) >= 32 ? 1 : 0;
}

// ---------------- KPREP: k0 (blocks<256) + k1m (blocks>=256) + cnt zero --
// The two parts are mutually independent; merged to cut dispatch count.
__global__ __launch_bounds__(256) void kprep(const void* __restrict__ w, const void* __restrict__ a,
                                             const int* __restrict__ adj,
                                             u16* __restrict__ wt, float* __restrict__ wa1,
                                             float* __restrict__ wa2, u64* __restrict__ mb64,
                                             int* __restrict__ cnt, const u32* __restrict__ hw) {
    __shared__ float s1[4], s2[4];
    int bid = blockIdx.x, t = threadIdx.x;
    int wid = t >> 6, lane = t & 63;
    if (bid < 256) {
        // ---- k0 verbatim: WT col + Wa1/Wa2 row-reduce ----
        if (bid == 0 && t < 8) cnt[t] = 0;
        int f32 = detect_f32(hw);
        int k = bid, o = t;
        float wv = ldany(w, (size_t)k * 256 + o, f32);
        wt[o * 256 + k] = f2bf(wv);
        float p1 = wv * ldany(a, o, f32);
        float p2 = wv * ldany(a, 256 + o, f32);
        for (int d = 32; d; d >>= 1) { p1 += __shfl_down(p1, d); p2 += __shfl_down(p2, d); }
        if (lane == 0) { s1[wid] = p1; s2[wid] = p2; }
        __syncthreads();
        if (o == 0) { wa1[k] = s1[0] + s1[1] + s1[2] + s1[3]; wa2[k] = s2[0] + s2[1] + s2[2] + s2[3]; }
    } else {
        // ---- k1m verbatim: mask bitset ----
        int b2 = bid - 256;
        #pragma unroll
        for (int q = 0; q < 4; q++) {
            int idx = b2 * 16 + wid * 4 + q;           // 65536 words
            int mrow = idx >> 5, c = idx & 31;
            int j = c * 64 + lane;
            bool bit = (adj[(size_t)mrow * 2048 + j] > 0) || (j == mrow);
            u64 m = __ballot(bit);
            if (lane == 0) mb64[(size_t)mrow * 32 + c] = m;
        }
    }
}

// ---------------- K2: Whb_t = bf16((h@W)^T) + EXACT fp32 s_i/s_j ---------
// (R4-verified 512-thr version, unchanged.)
struct __align__(16) K2LDS {
    u16 At[64 * 68];
    union { u16 Bt[256 * 68]; u16 Ct[256 * 68]; };
    float wa1s[256], wa2s[256];
    float s1[64], s2[64];
};
__global__ __launch_bounds__(512) void k2(const void* __restrict__ h, const u16* __restrict__ wt,
                                          const float* __restrict__ wa1, const float* __restrict__ wa2,
                                          u16* __restrict__ whbt,
                                          float* __restrict__ sig, float* __restrict__ sjg) {
    __shared__ K2LDS L;
    int f32 = detect_f32((const u32*)h);
    int m0 = blockIdx.x * 64;
    int b  = m0 >> 11;
    int n0 = m0 & 2047;
    int t = threadIdx.x;
    int wid = t >> 6, lane = t & 63, ln = lane & 15, qd = lane >> 4;

    if (t < 256) { L.wa1s[t] = wa1[t]; L.wa2s[t] = wa2[t]; }
    if (t < 64) { L.s1[t] = 0.f; L.s2[t] = 0.f; }
    __syncthreads();

    float a1 = 0.f, a2 = 0.f;

    f32x4 acc[4][2];
    for (int mi = 0; mi < 4; mi++)
        for (int ni = 0; ni < 2; ni++)
            acc[mi][ni] = (f32x4){0.f, 0.f, 0.f, 0.f};

    for (int c = 0; c < 4; c++) {
        int k0c = c * 64;
        {
            int r = t >> 3, s = t & 7;              // 64 rows x 8 octets = 512
            float xv[8]; u16 uv[8];
            if (f32) {
                const float* src = (const float*)h + (size_t)(m0 + r) * 256 + k0c + s * 8;
                f32x4 x0 = *(const f32x4*)src;
                f32x4 x1 = *(const f32x4*)(src + 4);
                #pragma unroll
                for (int q = 0; q < 4; q++) { xv[q] = x0[q]; xv[4 + q] = x1[q]; }
                #pragma unroll
                for (int q = 0; q < 8; q++) uv[q] = f2bf(xv[q]);
            } else {
                const u16* src = (const u16*)h + (size_t)(m0 + r) * 256 + k0c + s * 8;
                *(uint4*)uv = *(const uint4*)src;
                #pragma unroll
                for (int q = 0; q < 8; q++) xv[q] = bf2f(uv[q]);
            }
            *(uint4*)&L.At[r * 68 + s * 8] = *(uint4*)uv;
            float pa = 0.f, pb = 0.f;
            #pragma unroll
            for (int q = 0; q < 8; q++) {
                pa += xv[q] * L.wa1s[k0c + s * 8 + q];
                pb += xv[q] * L.wa2s[k0c + s * 8 + q];
            }
            a1 += pa; a2 += pb;
        }
        #pragma unroll
        for (int p = 0; p < 4; p++) {
            int f = (t >> 3) + p * 64, s = t & 7;   // 256 f rows over 4 phases
            *(uint4*)&L.Bt[f * 68 + s * 8] =
                *(const uint4*)(wt + (size_t)f * 256 + k0c + s * 8);
        }
        __syncthreads();
        for (int ks = 0; ks < 2; ks++) {
            bf16x8 af[4], bfr[2];
            for (int mi = 0; mi < 4; mi++)
                af[mi] = *(const bf16x8*)&L.At[(mi * 16 + ln) * 68 + ks * 32 + qd * 8];
            for (int ni = 0; ni < 2; ni++)
                bfr[ni] = *(const bf16x8*)&L.Bt[(wid * 32 + ni * 16 + ln) * 68 + ks * 32 + qd * 8];
            for (int mi = 0; mi < 4; mi++)
                for (int ni = 0; ni < 2; ni++)
                    acc[mi][ni] = MFMA_BF16(af[mi], bfr[ni], acc[mi][ni]);
        }
        __syncthreads();
    }

    // s partials: 8 threads per row (t>>3 = row)
    atomicAdd(&L.s1[t >> 3], a1);
    atomicAdd(&L.s2[t >> 3], a2);

    // transpose via LDS: Ct[f][n-local], then contiguous linear stores
    for (int mi = 0; mi < 4; mi++) {
        for (int ni = 0; ni < 2; ni++) {
            int f = wid * 32 + ni * 16 + ln;
            int n = mi * 16 + qd * 4;
            u16 v[4];
            for (int r = 0; r < 4; r++) v[r] = f2bf(acc[mi][ni][r]);
            *(uint2*)&L.Ct[f * 68 + n] = *(uint2*)v;
        }
    }
    __syncthreads();
    if (t < 64) { sig[m0 + t] = L.s1[t]; sjg[m0 + t] = L.s2[t]; }
    {
        int fr = t >> 1, hf = t & 1;               // 256 rows x 2 halves
        size_t base = (size_t)b * 524288 + (size_t)fr * 2048 + n0;
        #pragma unroll
        for (int k = 0; k < 4; k++) {
            int s = hf * 4 + k;
            uint4 v = *(uint4*)&L.Ct[fr * 68 + s * 8];
            *(uint4*)(whbt + base + s * 8) = v;
        }
    }
}

// ---------------- K4': k4 (R4-proven core) + inlined k3n table-gen -------
// Each block computes its batch's softmax tables itself from si/sj:
// Mb = max(sj[b]) (exact, order-independent), then vpack/sjb/u1/u2/nsi
// into the same LDS slots PGEN reads. Identical formulas to k3n (Mb
// cancels in the softmax ratio). Main loop / br dbuf / Pt layout
// untouched (32-VGPR br dbuf required — R3 lesson).
struct __align__(16) K4LDS {
    u32   vpack[2048];                 // 8192 B
    u16   sjb[2048];                   // 4096 B
    u64   mw[64 * 33];                 // 16896 B
    float u1[64], u2[64], nsi[64], inv[64];
    float lred[1024];                  // 4096 B
    u16   Pt[2][8192];                 // 2 x 16384 B, [octet][row][8]
    int   claim[2];
};
__global__ __launch_bounds__(1024, 4) void k4(const float* __restrict__ sig,
                                              const float* __restrict__ sjg,
                                              const u64* __restrict__ mb64, const u16* __restrict__ whbt,
                                              void* __restrict__ out, const void* __restrict__ hdet,
                                              int* __restrict__ cnt) {
    __shared__ K4LDS L;
    int f32 = detect_f32((const u32*)hdet);
    int t = threadIdx.x;
    if (t == 0) {
        // HW_REG_XCC_ID = id 20, offset 0, size 32 -> imm = 20 | (31<<11)
        int xcd = __builtin_amdgcn_s_getreg(63508) & 7;
        int bsel = 0, tile = 0;
        #pragma unroll
        for (int k = 0; k < 8; k++) {
            int bb = (xcd + k) & 7;
            int tt = atomicAdd(&cnt[bb], 1);
            if (tt < 32) { bsel = bb; tile = tt; break; }
        }
        L.claim[0] = bsel; L.claim[1] = tile;
    }
    __syncthreads();
    int b  = L.claim[0];
    int i0 = L.claim[1] * 64;
    int wid = t >> 6, lane = t & 63, ln = lane & 15, qd = lane >> 4;
    const u16* wb = whbt + (size_t)b * 524288 + (size_t)wid * 16 * 2048;
    float lacc = 0.f;

    // B frags for chunk cc: wave owns f-rows wid*16..+15 (no duplication)
    bf16x8 br[2][4];
    #define LOAD_B(cc, bb) do {                                             \
        int j0_ = (cc) * 128;                                               \
        _Pragma("unroll")                                                   \
        for (int ks = 0; ks < 4; ks++)                                      \
            br[bb][ks] = *(const bf16x8*)(wb +                              \
                (size_t)ln * 2048 + j0_ + ks * 32 + qd * 8);                \
    } while (0)

    // Factored P-gen: thread -> row (t&63), j-octet (t>>6); accumulates lacc.
    #define PGEN(cc, bb) do {                                               \
        int r_ = t & 63, o_ = t >> 6;                                       \
        int jb_ = (cc) * 128 + o_ * 8;                                      \
        uint4 pkA_ = *(const uint4*)&L.vpack[jb_];                          \
        uint4 pkB_ = *(const uint4*)&L.vpack[jb_ + 4];                      \
        uint4 sj4_ = *(const uint4*)&L.sjb[jb_];                            \
        u32 mb_ = (u32)(L.mw[r_ * 33 + 2 * (cc) + (o_ >> 3)]                \
                        >> ((o_ & 7) * 8)) & 0xffu;                         \
        float u1_ = L.u1[r_], u2_ = L.u2[r_], nsi_ = L.nsi[r_];             \
        u32 pr_[4];                                                         \
        _Pragma("unroll")                                                   \
        for (int pk = 0; pk < 4; pk++) {                                    \
            u32 vw0_ = (pk == 0) ? pkA_.x : (pk == 1) ? pkA_.z              \
                     : (pk == 2) ? pkB_.x : pkB_.z;                         \
            u32 vw1_ = (pk == 0) ? pkA_.y : (pk == 1) ? pkA_.w              \
                     : (pk == 2) ? pkB_.y : pkB_.w;                         \
            u32 sw_ = (pk == 0) ? sj4_.x : (pk == 1) ? sj4_.y               \
                     : (pk == 2) ? sj4_.z : sj4_.w;                         \
            float sj0_ = __uint_as_float(sw_ << 16);                        \
            float sj1_ = __uint_as_float(sw_ & 0xffff0000u);                \
            float p0_, p1_;                                                 \
            {                                                               \
                bool pos = sj0_ > nsi_;                                     \
                float vv = __uint_as_float(pos ? (vw0_ << 16)               \
                                               : ((vw0_ >> 16) << 16));     \
                p0_ = (pos ? u1_ : u2_) * vv;                               \
                p0_ = ((mb_ >> (2 * pk)) & 1u) ? p0_ : 0.f;                 \
            }                                                               \
            {                                                               \
                bool pos = sj1_ > nsi_;                                     \
                float vv = __uint_as_float(pos ? (vw1_ << 16)               \
                                               : ((vw1_ >> 16) << 16));     \
                p1_ = (pos ? u1_ : u2_) * vv;                               \
                p1_ = ((mb_ >> (2 * pk + 1)) & 1u) ? p1_ : 0.f;             \
            }                                                               \
            lacc += p0_ + p1_;                                              \
            pr_[pk] = __builtin_amdgcn_perm(__float_as_uint(p1_),           \
                                            __float_as_uint(p0_),           \
                                            0x07060302u);                   \
        }                                                                   \
        *(uint4*)&L.Pt[bb][t * 8] = *(uint4*)pr_;                           \
    } while (0)

    LOAD_B(0, 0);
    // ---- inlined k3n: per-batch shift + factored-exp tables ----
    float sjv0 = sjg[b * 2048 + t];
    float sjv1 = sjg[b * 2048 + 1024 + t];
    {
        float mx = fmaxf(sjv0, sjv1);
        for (int d = 32; d; d >>= 1) mx = fmaxf(mx, __shfl_xor(mx, d));
        if (lane == 0) L.lred[wid] = mx;
    }
    // stage mask words (2048 u64)
    for (int p = 0; p < 2; p++) {
        int idx = t + p * 1024;
        int r = idx >> 5, c = idx & 31;
        L.mw[r * 33 + c] = mb64[(size_t)(i0 + r) * 32 + c];
    }
    __syncthreads();
    float Mb;
    {
        float m0_ = fmaxf(fmaxf(fmaxf(L.lred[0], L.lred[1]), fmaxf(L.lred[2], L.lred[3])),
                          fmaxf(fmaxf(L.lred[4], L.lred[5]), fmaxf(L.lred[6], L.lred[7])));
        float m1_ = fmaxf(fmaxf(fmaxf(L.lred[8], L.lred[9]), fmaxf(L.lred[10], L.lred[11])),
                          fmaxf(fmaxf(L.lred[12], L.lred[13]), fmaxf(L.lred[14], L.lred[15])));
        Mb = fmaxf(m0_, m1_);
    }
    {
        float vj0 = __expf(sjv0 - Mb), v2j0 = __expf(0.2f * (sjv0 - Mb));
        L.vpack[t] = (u32)f2bf(vj0) | ((u32)f2bf(v2j0) << 16);
        L.sjb[t] = f2bf(sjv0);
        float vj1 = __expf(sjv1 - Mb), v2j1 = __expf(0.2f * (sjv1 - Mb));
        L.vpack[t + 1024] = (u32)f2bf(vj1) | ((u32)f2bf(v2j1) << 16);
        L.sjb[t + 1024] = f2bf(sjv1);
    }
    if (t < 64) {
        float siv = sig[b * 2048 + i0 + t];
        float x = siv + Mb;
        float K = fmaxf(x, 0.2f * x);
        L.u1[t] = __expf(x - K);
        L.u2[t] = __expf(0.2f * x - K);
        L.nsi[t] = -siv;
    }
    __syncthreads();
    PGEN(0, 0);

    f32x4 acc[4];
    for (int mi = 0; mi < 4; mi++)
        acc[mi] = (f32x4){0.f, 0.f, 0.f, 0.f};

    // one barrier per 128-j chunk; B(c+1) regs + PGEN(c+1) overlap MFMA(c)
    #define STEP(c, cur, nxt) do {                                          \
        __syncthreads();                                                    \
        if ((c) < 15) { LOAD_B((c) + 1, nxt); PGEN((c) + 1, nxt); }         \
        __builtin_amdgcn_s_setprio(1);                                      \
        _Pragma("unroll")                                                   \
        for (int ks = 0; ks < 4; ks++) {                                    \
            bf16x8 af[4];                                                   \
            _Pragma("unroll")                                               \
            for (int mi = 0; mi < 4; mi++)                                  \
                af[mi] = *(const bf16x8*)&L.Pt[cur][((ks * 4 + qd) * 64 +   \
                                                     mi * 16 + ln) * 8];    \
            _Pragma("unroll")                                               \
            for (int mi = 0; mi < 4; mi++)                                  \
                acc[mi] = MFMA_BF16(af[mi], br[cur][ks], acc[mi]);          \
        }                                                                   \
        __builtin_amdgcn_s_setprio(0);                                      \
    } while (0)

    for (int cc = 0; cc < 8; cc++) {
        STEP(2 * cc,     0, 1);
        STEP(2 * cc + 1, 1, 0);
    }

    // reduce row sums l_i: 16 partials per row (t = octet*64 + row)
    __syncthreads();
    L.lred[t] = lacc;
    __syncthreads();
    if (t < 64) {
        float s = 0.f;
        #pragma unroll
        for (int q = 0; q < 16; q++) s += L.lred[q * 64 + t];
        L.inv[t] = 1.0f / s;
    }
    __syncthreads();

    // epilogue: h_prime = acc * inv_l, ELU, store
    {
        int fg = wid * 16 + ln;
        for (int mi = 0; mi < 4; mi++) {
            for (int reg = 0; reg < 4; reg++) {
                int rl = mi * 16 + qd * 4 + reg;
                float hp = acc[mi][reg] * L.inv[rl];
                float y = hp > 0.f ? hp : (__expf(hp) - 1.f);
                size_t idx = (size_t)(b * 2048 + i0 + rl) * 256 + fg;
                if (f32) ((float*)out)[idx] = y;
                else     ((u16*)out)[idx]   = f2bf(y);
            }
        }
    }
    #undef LOAD_B
    #undef PGEN
    #undef STEP
}

// ---------------- launch --------------------------------------------------
extern "C" void kernel_launch(void* const* d_in, const int* in_sizes, int n_in,
                              void* d_out, int out_size, void* d_ws, size_t ws_size,
                              hipStream_t stream) {
    const void* h   = d_in[0];              // (8,2048,256) fp32 (detected) or bf16
    const int*  adj = (const int*)d_in[1];  // int32 (2048,2048)
    const void* W   = d_in[2];              // (256,256)
    const void* a   = d_in[3];              // (512,1)

    char* ws = (char*)d_ws;
    u16*   WT    = (u16*)  (ws + 0);        // 131072
    float* si    = (float*)(ws + 131072);   // 65536
    float* sj    = (float*)(ws + 196608);   // 65536
    u64*   mb64  = (u64*)  (ws + 557056);   // 524288
    u16*   whbt  = (u16*)  (ws + 1081344);  // 8388608 (end 9469952)
    float* Wa1   = (float*)(ws + 9469952);  // 1024
    float* Wa2   = (float*)(ws + 9470976);  // 1024
    int*   cnt   = (int*)  (ws + 9472000);  // 32

    kprep<<<dim3(4352), dim3(256),  0, stream>>>(W, a, adj, WT, Wa1, Wa2, mb64, cnt, (const u32*)h);
    k2   <<<dim3(256),  dim3(512),  0, stream>>>(h, WT, Wa1, Wa2, whbt, si, sj);
    k4   <<<dim3(256),  dim3(1024), 0, stream>>>(si, sj, mb64, whbt, d_out, h, cnt);
}

// Round 7
// 129.955 us; speedup vs baseline: 1.8286x; 1.0220x over previous
//
#include <hip/hip_runtime.h>

typedef unsigned short u16;
typedef unsigned int   u32;
typedef unsigned long long u64;

typedef __bf16 bf16x8 __attribute__((ext_vector_type(8)));
typedef float  f32x4  __attribute__((ext_vector_type(4)));

#define MFMA_BF16(a,b,c) __builtin_amdgcn_mfma_f32_16x16x32_bf16((a),(b),(c),0,0,0)

__device__ __forceinline__ float bf2f(u16 u) {
    return __uint_as_float(((u32)u) << 16);
}
__device__ __forceinline__ u16 f2bf(float x) {
    u32 u = __float_as_uint(x);
    u += 0x7fffu + ((u >> 16) & 1u);   // RNE
    return (u16)(u >> 16);
}
__device__ __forceinline__ float ldany(const void* p, size_t i, int f32) {
    return f32 ? ((const float*)p)[i] : bf2f(((const u16*)p)[i]);
}
// fp32-vs-bf16 detect from first 64 words of h; identical in every wave.
__device__ __forceinline__ int detect_f32(const u32* hw) {
    u32 w = hw[threadIdx.x & 63];
    int e = (w >> 23) & 0xFF;
    u64 m = __ballot(e >= 64 && e <= 190);
    return __popcll(m) >= 32 ? 1 : 0;
}

// ---------------- KPREP: k0 (blocks<256) + mask (blocks>=256) + cnt ------
// Mask part rebuilt: int4 loads (16 B/lane), BOTH tasks' loads issued
// before any cross-lane op (2 KB in flight/wave), u64 words assembled via
// 4-step shfl_xor OR-reduce of per-lane nibbles (bit 4*(l&15)+b == j off).
__global__ __launch_bounds__(256) void kprep(const void* __restrict__ w, const void* __restrict__ a,
                                             const int* __restrict__ adj,
                                             u16* __restrict__ wt, float* __restrict__ wa1,
                                             float* __restrict__ wa2, u64* __restrict__ mb64,
                                             int* __restrict__ cnt, const u32* __restrict__ hw) {
    __shared__ float s1[4], s2[4];
    int bid = blockIdx.x, t = threadIdx.x;
    int wid = t >> 6, lane = t & 63;
    if (bid < 256) {
        // ---- k0 verbatim: WT col + Wa1/Wa2 row-reduce ----
        if (bid == 0 && t < 8) cnt[t] = 0;
        int f32 = detect_f32(hw);
        int k = bid, o = t;
        float wv = ldany(w, (size_t)k * 256 + o, f32);
        wt[o * 256 + k] = f2bf(wv);
        float p1 = wv * ldany(a, o, f32);
        float p2 = wv * ldany(a, 256 + o, f32);
        for (int d = 32; d; d >>= 1) { p1 += __shfl_down(p1, d); p2 += __shfl_down(p2, d); }
        if (lane == 0) { s1[wid] = p1; s2[wid] = p2; }
        __syncthreads();
        if (o == 0) { wa1[k] = s1[0] + s1[1] + s1[2] + s1[3]; wa2[k] = s2[0] + s2[1] + s2[2] + s2[3]; }
    } else {
        // ---- mask bitset: wave handles 2 tasks (row, 256-j chunk) ----
        int w2 = (bid - 256) * 4 + wid;               // 0..8191
        int4 v[2]; int rowv[2], jbv[2];
        #pragma unroll
        for (int s = 0; s < 2; s++) {
            int task = w2 * 2 + s;                    // 0..16383 = 2048 rows x 8
            int row = task >> 3, jb = (task & 7) * 256;
            rowv[s] = row; jbv[s] = jb;
            v[s] = *(const int4*)(adj + (size_t)row * 2048 + jb + lane * 4);
        }
        #pragma unroll
        for (int s = 0; s < 2; s++) {
            int row = rowv[s], jb = jbv[s];
            int j0 = jb + lane * 4;
            u32 nib = (u32)(v[s].x > 0 || j0     == row)
                    | ((u32)(v[s].y > 0 || j0 + 1 == row) << 1)
                    | ((u32)(v[s].z > 0 || j0 + 2 == row) << 2)
                    | ((u32)(v[s].w > 0 || j0 + 3 == row) << 3);
            // lanes (l&15)=0..7 -> lo word half, 8..15 -> hi word half
            u32 sh = 4 * (lane & 7);
            u32 lo = (lane & 8) ? 0u : (nib << sh);
            u32 hi = (lane & 8) ? (nib << sh) : 0u;
            #pragma unroll
            for (int d = 1; d <= 8; d <<= 1) {
                lo |= __shfl_xor(lo, d);
                hi |= __shfl_xor(hi, d);
            }
            if ((lane & 15) == 0)
                mb64[(size_t)row * 32 + (jb >> 6) + (lane >> 4)] =
                    (u64)lo | ((u64)hi << 32);
        }
    }
}

// ---------------- K2: Whb_t = bf16((h@W)^T) + EXACT fp32 s_i/s_j ---------
// 1024 thr (4 waves/SIMD): A-stage+dots on t<512, B-stage on t>=512 run in
// parallel; 16 waves x 16-f MFMA slices. (Structure verified in R5's P2.)
struct __align__(16) K2LDS {
    u16 At[64 * 68];
    union { u16 Bt[256 * 68]; u16 Ct[256 * 68]; };
    float wa1s[256], wa2s[256];
    float s1[64], s2[64];
};
__global__ __launch_bounds__(1024, 4) void k2(const void* __restrict__ h, const u16* __restrict__ wt,
                                              const float* __restrict__ wa1, const float* __restrict__ wa2,
                                              u16* __restrict__ whbt,
                                              float* __restrict__ sig, float* __restrict__ sjg) {
    __shared__ K2LDS L;
    int f32 = detect_f32((const u32*)h);
    int m0 = blockIdx.x * 64;
    int b  = m0 >> 11;
    int n0 = m0 & 2047;
    int t = threadIdx.x;
    int wid = t >> 6, lane = t & 63, ln = lane & 15, qd = lane >> 4;

    if (t < 256) { L.wa1s[t] = wa1[t]; L.wa2s[t] = wa2[t]; }
    if (t < 64) { L.s1[t] = 0.f; L.s2[t] = 0.f; }
    __syncthreads();

    float a1 = 0.f, a2 = 0.f;
    f32x4 acc[4];
    for (int mi = 0; mi < 4; mi++) acc[mi] = (f32x4){0.f, 0.f, 0.f, 0.f};

    for (int c = 0; c < 4; c++) {
        int k0c = c * 64;
        if (t < 512) {
            int r = t >> 3, s = t & 7;              // 64 rows x 8 octets
            float xv[8]; u16 uv[8];
            if (f32) {
                const float* src = (const float*)h + (size_t)(m0 + r) * 256 + k0c + s * 8;
                f32x4 x0 = *(const f32x4*)src;
                f32x4 x1 = *(const f32x4*)(src + 4);
                #pragma unroll
                for (int q = 0; q < 4; q++) { xv[q] = x0[q]; xv[4 + q] = x1[q]; }
                #pragma unroll
                for (int q = 0; q < 8; q++) uv[q] = f2bf(xv[q]);
            } else {
                const u16* src = (const u16*)h + (size_t)(m0 + r) * 256 + k0c + s * 8;
                *(uint4*)uv = *(const uint4*)src;
                #pragma unroll
                for (int q = 0; q < 8; q++) xv[q] = bf2f(uv[q]);
            }
            *(uint4*)&L.At[r * 68 + s * 8] = *(uint4*)uv;
            float pa = 0.f, pb = 0.f;
            #pragma unroll
            for (int q = 0; q < 8; q++) {
                pa += xv[q] * L.wa1s[k0c + s * 8 + q];
                pb += xv[q] * L.wa2s[k0c + s * 8 + q];
            }
            a1 += pa; a2 += pb;
        } else {
            int tt = t - 512;
            #pragma unroll
            for (int p = 0; p < 4; p++) {
                int f = (tt >> 3) + p * 64, s = tt & 7;   // 256 f rows
                *(uint4*)&L.Bt[f * 68 + s * 8] =
                    *(const uint4*)(wt + (size_t)f * 256 + k0c + s * 8);
            }
        }
        __syncthreads();
        for (int ks = 0; ks < 2; ks++) {
            bf16x8 af[4], bfr;
            for (int mi = 0; mi < 4; mi++)
                af[mi] = *(const bf16x8*)&L.At[(mi * 16 + ln) * 68 + ks * 32 + qd * 8];
            bfr = *(const bf16x8*)&L.Bt[(wid * 16 + ln) * 68 + ks * 32 + qd * 8];
            for (int mi = 0; mi < 4; mi++)
                acc[mi] = MFMA_BF16(af[mi], bfr, acc[mi]);
        }
        __syncthreads();
    }

    if (t < 512) {
        atomicAdd(&L.s1[t >> 3], a1);
        atomicAdd(&L.s2[t >> 3], a2);
    }
    // transpose via LDS: Ct[f][n-local], then contiguous linear stores
    for (int mi = 0; mi < 4; mi++) {
        int f = wid * 16 + ln;
        int n = mi * 16 + qd * 4;
        u16 v[4];
        for (int r = 0; r < 4; r++) v[r] = f2bf(acc[mi][r]);
        *(uint2*)&L.Ct[f * 68 + n] = *(uint2*)v;
    }
    __syncthreads();
    if (t < 64) { sig[m0 + t] = L.s1[t]; sjg[m0 + t] = L.s2[t]; }
    {
        int fr = t >> 2, q0 = (t & 3) * 2;          // 256 rows x 4 quarter-pairs
        size_t base = (size_t)b * 524288 + (size_t)fr * 2048 + n0;
        #pragma unroll
        for (int k = 0; k < 2; k++) {
            int s = q0 + k;
            uint4 v = *(uint4*)&L.Ct[fr * 68 + s * 8];
            *(uint4*)(whbt + base + s * 8) = v;
        }
    }
}

// ---------------- K4': R6-proven core (43.9 us) — UNCHANGED --------------
struct __align__(16) K4LDS {
    u32   vpack[2048];                 // 8192 B
    u16   sjb[2048];                   // 4096 B
    u64   mw[64 * 33];                 // 16896 B
    float u1[64], u2[64], nsi[64], inv[64];
    float lred[1024];                  // 4096 B
    u16   Pt[2][8192];                 // 2 x 16384 B, [octet][row][8]
    int   claim[2];
};
__global__ __launch_bounds__(1024, 4) void k4(const float* __restrict__ sig,
                                              const float* __restrict__ sjg,
                                              const u64* __restrict__ mb64, const u16* __restrict__ whbt,
                                              void* __restrict__ out, const void* __restrict__ hdet,
                                              int* __restrict__ cnt) {
    __shared__ K4LDS L;
    int f32 = detect_f32((const u32*)hdet);
    int t = threadIdx.x;
    if (t == 0) {
        // HW_REG_XCC_ID = id 20, offset 0, size 32 -> imm = 20 | (31<<11)
        int xcd = __builtin_amdgcn_s_getreg(63508) & 7;
        int bsel = 0, tile = 0;
        #pragma unroll
        for (int k = 0; k < 8; k++) {
            int bb = (xcd + k) & 7;
            int tt = atomicAdd(&cnt[bb], 1);
            if (tt < 32) { bsel = bb; tile = tt; break; }
        }
        L.claim[0] = bsel; L.claim[1] = tile;
    }
    __syncthreads();
    int b  = L.claim[0];
    int i0 = L.claim[1] * 64;
    int wid = t >> 6, lane = t & 63, ln = lane & 15, qd = lane >> 4;
    const u16* wb = whbt + (size_t)b * 524288 + (size_t)wid * 16 * 2048;
    float lacc = 0.f;

    // B frags for chunk cc: wave owns f-rows wid*16..+15 (no duplication)
    bf16x8 br[2][4];
    #define LOAD_B(cc, bb) do {                                             \
        int j0_ = (cc) * 128;                                               \
        _Pragma("unroll")                                                   \
        for (int ks = 0; ks < 4; ks++)                                      \
            br[bb][ks] = *(const bf16x8*)(wb +                              \
                (size_t)ln * 2048 + j0_ + ks * 32 + qd * 8);                \
    } while (0)

    // Factored P-gen: thread -> row (t&63), j-octet (t>>6); accumulates lacc.
    #define PGEN(cc, bb) do {                                               \
        int r_ = t & 63, o_ = t >> 6;                                       \
        int jb_ = (cc) * 128 + o_ * 8;                                      \
        uint4 pkA_ = *(const uint4*)&L.vpack[jb_];                          \
        uint4 pkB_ = *(const uint4*)&L.vpack[jb_ + 4];                      \
        uint4 sj4_ = *(const uint4*)&L.sjb[jb_];                            \
        u32 mb_ = (u32)(L.mw[r_ * 33 + 2 * (cc) + (o_ >> 3)]                \
                        >> ((o_ & 7) * 8)) & 0xffu;                         \
        float u1_ = L.u1[r_], u2_ = L.u2[r_], nsi_ = L.nsi[r_];             \
        u32 pr_[4];                                                         \
        _Pragma("unroll")                                                   \
        for (int pk = 0; pk < 4; pk++) {                                    \
            u32 vw0_ = (pk == 0) ? pkA_.x : (pk == 1) ? pkA_.z              \
                     : (pk == 2) ? pkB_.x : pkB_.z;                         \
            u32 vw1_ = (pk == 0) ? pkA_.y : (pk == 1) ? pkA_.w              \
                     : (pk == 2) ? pkB_.y : pkB_.w;                         \
            u32 sw_ = (pk == 0) ? sj4_.x : (pk == 1) ? sj4_.y               \
                     : (pk == 2) ? sj4_.z : sj4_.w;                         \
            float sj0_ = __uint_as_float(sw_ << 16);                        \
            float sj1_ = __uint_as_float(sw_ & 0xffff0000u);                \
            float p0_, p1_;                                                 \
            {                                                               \
                bool pos = sj0_ > nsi_;                                     \
                float vv = __uint_as_float(pos ? (vw0_ << 16)               \
                                               : ((vw0_ >> 16) << 16));     \
                p0_ = (pos ? u1_ : u2_) * vv;                               \
                p0_ = ((mb_ >> (2 * pk)) & 1u) ? p0_ : 0.f;                 \
            }                                                               \
            {                                                               \
                bool pos = sj1_ > nsi_;                                     \
                float vv = __uint_as_float(pos ? (vw1_ << 16)               \
                                               : ((vw1_ >> 16) << 16));     \
                p1_ = (pos ? u1_ : u2_) * vv;                               \
                p1_ = ((mb_ >> (2 * pk + 1)) & 1u) ? p1_ : 0.f;             \
            }                                                               \
            lacc += p0_ + p1_;                                              \
            pr_[pk] = __builtin_amdgcn_perm(__float_as_uint(p1_),           \
                                            __float_as_uint(p0_),           \
                                            0x07060302u);                   \
        }                                                                   \
        *(uint4*)&L.Pt[bb][t * 8] = *(uint4*)pr_;                           \
    } while (0)

    LOAD_B(0, 0);
    // ---- inlined k3n: per-batch shift + factored-exp tables ----
    float sjv0 = sjg[b * 2048 + t];
    float sjv1 = sjg[b * 2048 + 1024 + t];
    {
        float mx = fmaxf(sjv0, sjv1);
        for (int d = 32; d; d >>= 1) mx = fmaxf(mx, __shfl_xor(mx, d));
        if (lane == 0) L.lred[wid] = mx;
    }
    // stage mask words (2048 u64)
    for (int p = 0; p < 2; p++) {
        int idx = t + p * 1024;
        int r = idx >> 5, c = idx & 31;
        L.mw[r * 33 + c] = mb64[(size_t)(i0 + r) * 32 + c];
    }
    __syncthreads();
    float Mb;
    {
        float m0_ = fmaxf(fmaxf(fmaxf(L.lred[0], L.lred[1]), fmaxf(L.lred[2], L.lred[3])),
                          fmaxf(fmaxf(L.lred[4], L.lred[5]), fmaxf(L.lred[6], L.lred[7])));
        float m1_ = fmaxf(fmaxf(fmaxf(L.lred[8], L.lred[9]), fmaxf(L.lred[10], L.lred[11])),
                          fmaxf(fmaxf(L.lred[12], L.lred[13]), fmaxf(L.lred[14], L.lred[15])));
        Mb = fmaxf(m0_, m1_);
    }
    {
        float vj0 = __expf(sjv0 - Mb), v2j0 = __expf(0.2f * (sjv0 - Mb));
        L.vpack[t] = (u32)f2bf(vj0) | ((u32)f2bf(v2j0) << 16);
        L.sjb[t] = f2bf(sjv0);
        float vj1 = __expf(sjv1 - Mb), v2j1 = __expf(0.2f * (sjv1 - Mb));
        L.vpack[t + 1024] = (u32)f2bf(vj1) | ((u32)f2bf(v2j1) << 16);
        L.sjb[t + 1024] = f2bf(sjv1);
    }
    if (t < 64) {
        float siv = sig[b * 2048 + i0 + t];
        float x = siv + Mb;
        float K = fmaxf(x, 0.2f * x);
        L.u1[t] = __expf(x - K);
        L.u2[t] = __expf(0.2f * x - K);
        L.nsi[t] = -siv;
    }
    __syncthreads();
    PGEN(0, 0);

    f32x4 acc[4];
    for (int mi = 0; mi < 4; mi++)
        acc[mi] = (f32x4){0.f, 0.f, 0.f, 0.f};

    // one barrier per 128-j chunk; B(c+1) regs + PGEN(c+1) overlap MFMA(c)
    #define STEP(c, cur, nxt) do {                                          \
        __syncthreads();                                                    \
        if ((c) < 15) { LOAD_B((c) + 1, nxt); PGEN((c) + 1, nxt); }         \
        __builtin_amdgcn_s_setprio(1);                                      \
        _Pragma("unroll")                                                   \
        for (int ks = 0; ks < 4; ks++) {                                    \
            bf16x8 af[4];                                                   \
            _Pragma("unroll")                                               \
            for (int mi = 0; mi < 4; mi++)                                  \
                af[mi] = *(const bf16x8*)&L.Pt[cur][((ks * 4 + qd) * 64 +   \
                                                     mi * 16 + ln) * 8];    \
            _Pragma("unroll")                                               \
            for (int mi = 0; mi < 4; mi++)                                  \
                acc[mi] = MFMA_BF16(af[mi], br[cur][ks], acc[mi]);          \
        }                                                                   \
        __builtin_amdgcn_s_setprio(0);                                      \
    } while (0)

    for (int cc = 0; cc < 8; cc++) {
        STEP(2 * cc,     0, 1);
        STEP(2 * cc + 1, 1, 0);
    }

    // reduce row sums l_i: 16 partials per row (t = octet*64 + row)
    __syncthreads();
    L.lred[t] = lacc;
    __syncthreads();
    if (t < 64) {
        float s = 0.f;
        #pragma unroll
        for (int q = 0; q < 16; q++) s += L.lred[q * 64 + t];
        L.inv[t] = 1.0f / s;
    }
    __syncthreads();

    // epilogue: h_prime = acc * inv_l, ELU, store
    {
        int fg = wid * 16 + ln;
        for (int mi = 0; mi < 4; mi++) {
            for (int reg = 0; reg < 4; reg++) {
                int rl = mi * 16 + qd * 4 + reg;
                float hp = acc[mi][reg] * L.inv[rl];
                float y = hp > 0.f ? hp : (__expf(hp) - 1.f);
                size_t idx = (size_t)(b * 2048 + i0 + rl) * 256 + fg;
                if (f32) ((float*)out)[idx] = y;
                else     ((u16*)out)[idx]   = f2bf(y);
            }
        }
    }
    #undef LOAD_B
    #undef PGEN
    #undef STEP
}

// ---------------- launch --------------------------------------------------
extern "C" void kernel_launch(void* const* d_in, const int* in_sizes, int n_in,
                              void* d_out, int out_size, void* d_ws, size_t ws_size,
                              hipStream_t stream) {
    const void* h   = d_in[0];              // (8,2048,256) fp32 (detected) or bf16
    const int*  adj = (const int*)d_in[1];  // int32 (2048,2048)
    const void* W   = d_in[2];              // (256,256)
    const void* a   = d_in[3];              // (512,1)

    char* ws = (char*)d_ws;
    u16*   WT    = (u16*)  (ws + 0);        // 131072
    float* si    = (float*)(ws + 131072);   // 65536
    float* sj    = (float*)(ws + 196608);   // 65536
    u64*   mb64  = (u64*)  (ws + 557056);   // 524288
    u16*   whbt  = (u16*)  (ws + 1081344);  // 8388608 (end 9469952)
    float* Wa1   = (float*)(ws + 9469952);  // 1024
    float* Wa2   = (float*)(ws + 9470976);  // 1024
    int*   cnt   = (int*)  (ws + 9472000);  // 32

    kprep<<<dim3(2304), dim3(256),  0, stream>>>(W, a, adj, WT, Wa1, Wa2, mb64, cnt, (const u32*)h);
    k2   <<<dim3(256),  dim3(1024), 0, stream>>>(h, WT, Wa1, Wa2, whbt, si, sj);
    k4   <<<dim3(256),  dim3(1024), 0, stream>>>(si, sj, mb64, whbt, d_out, h, cnt);
}